// Round 17
// baseline (632.510 us; speedup 1.0000x reference)
//
#include <hip/hip_runtime.h>
#include <hip/hip_bf16.h>

using bf16 = __hip_bfloat16;
typedef __attribute__((ext_vector_type(8))) short bf16x8;
typedef __attribute__((ext_vector_type(4))) float f32x4;

#define DEV static __device__ __forceinline__
#define CFENCE asm volatile("" ::: "memory")

DEV float b2f(unsigned short u) {
    unsigned int v = ((unsigned int)u) << 16;
    float f;
    __builtin_memcpy(&f, &v, 4);
    return f;
}
DEV unsigned short f2b(float f) {
    union { bf16 h; unsigned short u; } cv;
    cv.h = __float2bfloat16(f);
    return cv.u;
}

DEV void gload_lds16(const void* g, void* l) {
    __builtin_amdgcn_global_load_lds((__attribute__((address_space(1))) void*)g,
                                     (__attribute__((address_space(3))) void*)l, 16, 0, 0);
}

// ---------------- prep: 5 weight transposes + silu(c), one launch ----------------
DEV void wcast_tile64(float (*tile)[65], const float* __restrict__ w, bf16* __restrict__ wt,
                      int K, int N, int id, int tid) {
    const int gxN = N >> 6;
    const int n0 = (id % gxN) << 6, k0 = (id / gxN) << 6;
    const int r = tid >> 4, c4 = (tid & 15) << 2;
#pragma unroll
    for (int i = 0; i < 4; i++) {
        float4 v = *(const float4*)(w + (size_t)(k0 + r + 16 * i) * N + n0 + c4);
        tile[r + 16 * i][c4] = v.x;
        tile[r + 16 * i][c4 + 1] = v.y;
        tile[r + 16 * i][c4 + 2] = v.z;
        tile[r + 16 * i][c4 + 3] = v.w;
    }
    __syncthreads();
#pragma unroll
    for (int i = 0; i < 4; i++) {
        int rn = r + 16 * i;
        ushort4 o;
        o.x = f2b(tile[c4][rn]);
        o.y = f2b(tile[c4 + 1][rn]);
        o.z = f2b(tile[c4 + 2][rn]);
        o.w = f2b(tile[c4 + 3][rn]);
        *(ushort4*)(wt + (size_t)(n0 + rn) * K + k0 + c4) = o;
    }
}

__global__ __launch_bounds__(256) void k_prep(
    const float* __restrict__ w_ada, const float* __restrict__ w_qkv,
    const float* __restrict__ w_proj, const float* __restrict__ w_fc1,
    const float* __restrict__ w_fc2, const float* __restrict__ c,
    bf16* __restrict__ o_ada, bf16* __restrict__ o_qkv, bf16* __restrict__ o_proj,
    bf16* __restrict__ o_fc1, bf16* __restrict__ o_fc2, bf16* __restrict__ o_silu) {
    __shared__ float tile[64][65];
    const int bid = blockIdx.x;
    const int tid = threadIdx.x;
    if (bid < 1536) {
        wcast_tile64(tile, w_ada, o_ada, 1024, 6144, bid, tid);
    } else if (bid < 2304) {
        wcast_tile64(tile, w_qkv, o_qkv, 1024, 3072, bid - 1536, tid);
    } else if (bid < 2560) {
        wcast_tile64(tile, w_proj, o_proj, 1024, 1024, bid - 2304, tid);
    } else if (bid < 3584) {
        wcast_tile64(tile, w_fc1, o_fc1, 1024, 4096, bid - 2560, tid);
    } else if (bid < 4608) {
        wcast_tile64(tile, w_fc2, o_fc2, 4096, 1024, bid - 3584, tid);
    } else {
        int i = (bid - 4608) * 256 + tid;
        float4 v = ((const float4*)c)[i];
        float a[4] = {v.x, v.y, v.z, v.w};
        ushort4 r;
        unsigned short* rp = (unsigned short*)&r;
#pragma unroll
        for (int j = 0; j < 4; j++) {
            float s = a[j] / (1.f + __expf(-a[j]));
            rp[j] = f2b(s);
        }
        ((ushort4*)o_silu)[i] = r;
    }
}

// ---------------- LayerNorm + modulate -> bf16 ----------------
__global__ __launch_bounds__(256) void k_ln_mod(const float* __restrict__ x,
                                                const bf16* __restrict__ mod,
                                                bf16* __restrict__ h,
                                                int shift_off, int scale_off) {
    int row = blockIdx.x;
    int t = threadIdx.x;
    float4 v = ((const float4*)(x + (size_t)row * 1024))[t];
    float sum = v.x + v.y + v.z + v.w;
    float sq = v.x * v.x + v.y * v.y + v.z * v.z + v.w * v.w;
#pragma unroll
    for (int off = 32; off > 0; off >>= 1) {
        sum += __shfl_xor(sum, off);
        sq += __shfl_xor(sq, off);
    }
    __shared__ float s_sum[4], s_sq[4];
    if ((t & 63) == 0) { s_sum[t >> 6] = sum; s_sq[t >> 6] = sq; }
    __syncthreads();
    sum = s_sum[0] + s_sum[1] + s_sum[2] + s_sum[3];
    sq = s_sq[0] + s_sq[1] + s_sq[2] + s_sq[3];
    float mu = sum * (1.f / 1024.f);
    float var = sq * (1.f / 1024.f) - mu * mu;
    float rstd = rsqrtf(var + 1e-6f);
    const unsigned short* mrow = (const unsigned short*)mod + (size_t)row * 6144;
    ushort4 sh = ((const ushort4*)(mrow + shift_off))[t];
    ushort4 sc = ((const ushort4*)(mrow + scale_off))[t];
    unsigned short shs[4] = {sh.x, sh.y, sh.z, sh.w};
    unsigned short scs[4] = {sc.x, sc.y, sc.z, sc.w};
    float a[4] = {v.x, v.y, v.z, v.w};
    ushort4 r;
    unsigned short* rp = (unsigned short*)&r;
#pragma unroll
    for (int j = 0; j < 4; j++) {
        float nv = (a[j] - mu) * rstd;
        rp[j] = f2b(nv * (1.f + b2f(scs[j])) + b2f(shs[j]));
    }
    ((ushort4*)(h + (size_t)row * 1024))[t] = r;
}

enum { EPI_BF16 = 0, EPI_QKV = 1, EPI_RES = 2, EPI_GELU = 3, EPI_PART = 4 };

// bijective XCD-chunked + 8-wide column-group decomposition (works for any gx)
DEV void grid_decomp(int bid, int gx, int gy, int& by, int& bx) {
    const int nwg = gx * gy, cpx = nwg >> 3;  // requires nwg % 8 == 0
    const int wg = (bid & 7) * cpx + (bid >> 3);
    const int gspan = 8 * gy;
    const int grp = wg / gspan, rem = wg - grp * gspan;
    const int rest = gx - grp * 8;
    const int gw = rest < 8 ? rest : 8;  // last group may be narrower
    by = rem / gw;
    bx = grp * 8 + (rem - by * gw);
}

// ---------------- 128x128 GEMM, 2-wave blocks, wave-tile 128x64 ----------------
// 128 threads = 2 waves (N-halves), each wave computes 128x64 -> LDS bytes/FLOP
// = 0.75x of the 64x64 scheme (the measured binding pipe was LDS reads at ~100%).
// Single 32 KiB buffer, reg-hoisted fragments, lgkmcnt(0)+barrier -> stage(kt+1)
// overlapping MFMA -> vmcnt(0)+barrier. ~190 VGPR -> (128,2) cap 256, 4 blocks/CU.
// NOTE R14: over-aggressive bounds clamp VGPR and spill catastrophically.
template <int EPI>
__global__ __launch_bounds__(128, 2) void k_gemm128(
    const bf16* __restrict__ A, const bf16* __restrict__ Bt, const float* __restrict__ bias,
    int M, int N, int K, int kseg,
    bf16* __restrict__ outb,
    bf16* __restrict__ qo, bf16* __restrict__ ko, bf16* __restrict__ vto,
    const float* __restrict__ resid, const bf16* __restrict__ mod, int gate_off,
    float* __restrict__ outf) {
    __shared__ char lds[32768];  // A[128][64] 16K + B[128][64] 16K
    const int tid = threadIdx.x, wave = tid >> 6, lane = tid & 63;
    const int lr = lane & 15, lg = lane >> 4;

    int by, bx;
    grid_decomp((int)blockIdx.x, N >> 7, M >> 7, by, bx);
    const int row0 = by << 7, col0 = bx << 7;
    const int seg = blockIdx.y;

    f32x4 acc[8][4] = {};

    const size_t Kb = (size_t)K * 2;
    const size_t rowstep = Kb << 4;  // 16 rows
    const char* Ag = (const char*)A + (size_t)row0 * Kb + (size_t)seg * kseg * 2;
    const char* Bg = (const char*)Bt + (size_t)col0 * Kb + (size_t)seg * kseg * 2;

    // staging: 128 threads; thread covers rows grow+16i (i=0..7), 16B chunk (tid&7)
    const int grow = tid >> 3;
    const unsigned gsw = (unsigned)(((tid & 7) ^ (grow & 7)) << 4);
    const char* gA0 = Ag + (size_t)grow * Kb + gsw;
    const char* gB0 = Bg + (size_t)grow * Kb + gsw;

    auto stage = [&](int kt) {
        char* d = lds + (tid << 4);
        const size_t ko = (size_t)kt * 128;
#pragma unroll
        for (int i = 0; i < 8; i++)
            gload_lds16(gA0 + i * rowstep + ko, d + i * 2048);
#pragma unroll
        for (int i = 0; i < 8; i++)
            gload_lds16(gB0 + i * rowstep + ko, d + 16384 + i * 2048);
    };

    // LDS read bases (lane-constant swizzle: frag row = 16*m + lr -> row&7 == lr&7)
    const unsigned sw = (unsigned)((lr & 7) << 4);
    const unsigned swz0 = ((unsigned)(lg * 16)) ^ sw;        // kk=0
    const unsigned swz1 = ((unsigned)(64 + lg * 16)) ^ sw;   // kk=1
    const unsigned aoff = (unsigned)(lr * 128);
    const unsigned boff = (unsigned)(16384 + wave * 8192 + lr * 128);

    stage(0);
    const int NT = kseg >> 6;
    asm volatile("s_waitcnt vmcnt(0)" ::: "memory");
    __builtin_amdgcn_s_barrier();
    CFENCE;

    for (int kt = 0; kt < NT; ++kt) {
        bf16x8 a0[8], a1[8], b0[4], b1[4];
#pragma unroll
        for (int m = 0; m < 8; m++) {
            a0[m] = *(const bf16x8*)(lds + aoff + m * 2048 + swz0);
            a1[m] = *(const bf16x8*)(lds + aoff + m * 2048 + swz1);
        }
#pragma unroll
        for (int nj = 0; nj < 4; nj++) {
            b0[nj] = *(const bf16x8*)(lds + boff + nj * 2048 + swz0);
            b1[nj] = *(const bf16x8*)(lds + boff + nj * 2048 + swz1);
        }
        asm volatile("s_waitcnt lgkmcnt(0)" ::: "memory");
        __builtin_amdgcn_s_barrier();  // all waves finished reading the buffer
        CFENCE;
        if (kt + 1 < NT) stage(kt + 1);  // write same buffer, overlaps MFMA below
        __builtin_amdgcn_s_setprio(1);
#pragma unroll
        for (int m = 0; m < 8; m++)
#pragma unroll
            for (int nj = 0; nj < 4; nj++) {
                acc[m][nj] = __builtin_amdgcn_mfma_f32_16x16x32_bf16(a0[m], b0[nj], acc[m][nj], 0, 0, 0);
                acc[m][nj] = __builtin_amdgcn_mfma_f32_16x16x32_bf16(a1[m], b1[nj], acc[m][nj], 0, 0, 0);
            }
        __builtin_amdgcn_s_setprio(0);
        CFENCE;
        asm volatile("s_waitcnt vmcnt(0)" ::: "memory");
        __builtin_amdgcn_s_barrier();  // kt+1 tile fully landed
        CFENCE;
    }

    // epilogue: wave covers rows row0..+127, cols col0 + wave*64 .. +63
    const int rbase = row0 + 4 * lg;
    const int cbase = col0 + wave * 64 + lr;
#pragma unroll
    for (int mi = 0; mi < 8; mi++) {
#pragma unroll
        for (int nj = 0; nj < 4; nj++) {
            int col = cbase + 16 * nj;
            float bs = (EPI == EPI_PART) ? 0.f : bias[col];
#pragma unroll
            for (int r = 0; r < 4; r++) {
                int row = rbase + 16 * mi + r;
                float v = acc[mi][nj][r] + bs;
                if constexpr (EPI == EPI_BF16) {
                    outb[(size_t)row * N + col] = __float2bfloat16(v);
                } else if constexpr (EPI == EPI_GELU) {
                    float u = 0.7978845608f * (v + 0.044715f * v * v * v);
                    float e = __expf(2.f * u);
                    float th = 1.f - 2.f / (e + 1.f);
                    outb[(size_t)row * N + col] = __float2bfloat16(0.5f * v * (1.f + th));
                } else if constexpr (EPI == EPI_RES) {
                    float gate = b2f(((const unsigned short*)mod)[(size_t)row * 6144 + gate_off + col]);
                    outf[(size_t)row * N + col] = resid[(size_t)row * N + col] + gate * v;
                } else if constexpr (EPI == EPI_PART) {
                    outf[((size_t)seg * M + row) * N + col] = v;
                } else {  // EPI_QKV
                    int tt = col >> 10, hh = (col >> 6) & 15, d = col & 63;
                    int bb = row >> 10, ll = row & 1023;
                    size_t bh = (size_t)bb * 16 + hh;
                    bf16 bv = __float2bfloat16(v);
                    if (tt == 0) qo[(bh * 1024 + ll) * 64 + d] = bv;
                    else if (tt == 1) ko[(bh * 1024 + ll) * 64 + d] = bv;
                    else vto[(bh * 64 + d) * 1024 + ll] = bv;
                }
            }
        }
    }
}

// ---------------- split-K reduce: out = resid + gate * (sum partials + bias) ----------------
template <int NS>
__global__ __launch_bounds__(256) void k_reduce4(
    const float* __restrict__ part, const float* __restrict__ resid,
    const bf16* __restrict__ mod, int gate_off, const float* __restrict__ bias,
    float* __restrict__ out) {
    const int total4 = 4096 * 1024 / 4;
    for (int i = blockIdx.x * 256 + threadIdx.x; i < total4; i += gridDim.x * 256) {
        int row = i >> 8;
        int c4 = (i & 255) << 2;
        float4 s = ((const float4*)part)[i];
#pragma unroll
        for (int sg = 1; sg < NS; sg++) {
            float4 t = ((const float4*)part)[(size_t)sg * total4 + i];
            s.x += t.x; s.y += t.y; s.z += t.z; s.w += t.w;
        }
        float4 bi = *(const float4*)(bias + c4);
        ushort4 g = *(const ushort4*)((const unsigned short*)mod + (size_t)row * 6144 + gate_off + c4);
        float4 rs = ((const float4*)resid)[i];
        float4 o;
        o.x = rs.x + b2f(g.x) * (s.x + bi.x);
        o.y = rs.y + b2f(g.y) * (s.y + bi.y);
        o.z = rs.z + b2f(g.z) * (s.z + bi.z);
        o.w = rs.w + b2f(g.w) * (s.w + bi.w);
        ((float4*)out)[i] = o;
    }
}

// ---------------- fused: x1 = resid + gate*(sum part + bias); h = modulate(LN(x1)) ----
__global__ __launch_bounds__(256) void k_reduce_ln(
    const float* __restrict__ part, const float* __restrict__ resid,
    const bf16* __restrict__ mod, const float* __restrict__ bias,
    float* __restrict__ x1, bf16* __restrict__ h,
    int gate_off, int shift_off, int scale_off) {
    const int row = blockIdx.x, t = threadIdx.x;
    const int total4 = 4096 * 1024 / 4;
    const int i = row * 256 + t;
    const unsigned short* mrow = (const unsigned short*)mod + (size_t)row * 6144;

    float4 s = ((const float4*)part)[i];
    float4 s1 = ((const float4*)part)[total4 + i];
    s.x += s1.x; s.y += s1.y; s.z += s1.z; s.w += s1.w;
    float4 bi = ((const float4*)bias)[t];
    ushort4 g = ((const ushort4*)(mrow + gate_off))[t];
    float4 rs = ((const float4*)resid)[i];
    float4 xv;
    xv.x = rs.x + b2f(g.x) * (s.x + bi.x);
    xv.y = rs.y + b2f(g.y) * (s.y + bi.y);
    xv.z = rs.z + b2f(g.z) * (s.z + bi.z);
    xv.w = rs.w + b2f(g.w) * (s.w + bi.w);
    ((float4*)x1)[i] = xv;

    float sum = xv.x + xv.y + xv.z + xv.w;
    float sq = xv.x * xv.x + xv.y * xv.y + xv.z * xv.z + xv.w * xv.w;
#pragma unroll
    for (int off = 32; off > 0; off >>= 1) {
        sum += __shfl_xor(sum, off);
        sq += __shfl_xor(sq, off);
    }
    __shared__ float s_sum[4], s_sq[4];
    if ((t & 63) == 0) { s_sum[t >> 6] = sum; s_sq[t >> 6] = sq; }
    __syncthreads();
    sum = s_sum[0] + s_sum[1] + s_sum[2] + s_sum[3];
    sq = s_sq[0] + s_sq[1] + s_sq[2] + s_sq[3];
    float mu = sum * (1.f / 1024.f);
    float var = sq * (1.f / 1024.f) - mu * mu;
    float rstd = rsqrtf(var + 1e-6f);
    ushort4 sh = ((const ushort4*)(mrow + shift_off))[t];
    ushort4 sc = ((const ushort4*)(mrow + scale_off))[t];
    unsigned short shs[4] = {sh.x, sh.y, sh.z, sh.w};
    unsigned short scs[4] = {sc.x, sc.y, sc.z, sc.w};
    float a[4] = {xv.x, xv.y, xv.z, xv.w};
    ushort4 r;
    unsigned short* rp = (unsigned short*)&r;
#pragma unroll
    for (int j = 0; j < 4; j++) {
        float nv = (a[j] - mu) * rstd;
        rp[j] = f2b(nv * (1.f + b2f(scs[j])) + b2f(shs[j]));
    }
    ((ushort4*)(h + (size_t)row * 1024))[t] = r;
}

// ---------------- flash attention: swapped QK^T (lane-local softmax) ----------------
__global__ __launch_bounds__(256) void k_attn(const bf16* __restrict__ qb,
                                              const bf16* __restrict__ kb,
                                              const bf16* __restrict__ vtb,
                                              bf16* __restrict__ ob) {
    __shared__ bf16 Ks[2][4096];
    __shared__ bf16 Vs[2][4096];
    __shared__ bf16 Ps[4][1024];
    const int tid = threadIdx.x, wave = tid >> 6, lane = tid & 63;
    const int flat = blockIdx.x;
    const int wg = (flat & 7) * 128 + (flat >> 3);
    const int bh = wg >> 4;
    const int q0 = (wg & 15) * 64;
    const int b = bh >> 4, hh = bh & 15;
    const int lr = lane & 15, lg = lane >> 4, lk = lg * 8;

    const char* kbase = (const char*)(kb + (size_t)bh * 65536);
    const char* vbase = (const char*)(vtb + (size_t)bh * 65536);

    const int srow = tid >> 3;
    const int schunk = (tid & 7) ^ (srow & 7);

    bf16x8 qf[2];
    {
        const float C2 = 0.18033688f;  // 0.125 * log2(e)
        const bf16* qp = qb + ((size_t)bh * 1024 + q0 + 16 * wave + lr) * 64 + lk;
        bf16x8 t0 = *(const bf16x8*)qp;
        bf16x8 t1 = *(const bf16x8*)(qp + 32);
#pragma unroll
        for (int e = 0; e < 8; e++) {
            qf[0][e] = f2b(b2f((unsigned short)t0[e]) * C2);
            qf[1][e] = f2b(b2f((unsigned short)t1[e]) * C2);
        }
    }

    f32x4 oacc[4] = {};
    f32x4 l_v = {};
    float m_s = -1e30f;

    char* pwb = (char*)&Ps[wave][0];
    const unsigned psw = (unsigned)((lr & 7) << 4);
    unsigned pwr[4], prd[2];
#pragma unroll
    for (int j = 0; j < 4; j++) pwr[j] = ((unsigned)(lr * 128 + 32 * j + 8 * lg)) ^ psw;
#pragma unroll
    for (int ks = 0; ks < 2; ks++) prd[ks] = ((unsigned)(lr * 128 + 64 * ks + 16 * lg)) ^ psw;
    unsigned vb_in[2];
#pragma unroll
    for (int ks = 0; ks < 2; ks++)
        vb_in[ks] = ((unsigned)(128 * lr + 64 * ks + 2 * lk)) ^ psw;
    bf16x8 vone;
#pragma unroll
    for (int e = 0; e < 8; e++) vone[e] = (short)0x3F80;

    auto stage = [&](int kv0, int cur) {
#pragma unroll
        for (int i = 0; i < 2; i++) {
            int row = i * 32 + srow;
            gload_lds16(kbase + (size_t)(kv0 + row) * 128 + schunk * 16,
                        (char*)&Ks[cur][0] + wave * 1024 + i * 4096);
            gload_lds16(vbase + (size_t)row * 2048 + (size_t)kv0 * 2 + schunk * 16,
                        (char*)&Vs[cur][0] + wave * 1024 + i * 4096);
        }
    };

    stage(0, 0);
    __syncthreads();

    for (int t = 0; t < 16; ++t) {
        const int cur = t & 1;
        if (t + 1 < 16) stage((t + 1) * 64, cur ^ 1);
        const char* kc = (const char*)&Ks[cur][0];
        const char* vc = (const char*)&Vs[cur][0];

        f32x4 s[4] = {};
#pragma unroll
        for (int j = 0; j < 4; j++) {
            int row = 16 * j + lr;
            int sw = (row & 7) << 4;
            bf16x8 k0 = *(const bf16x8*)(kc + ((row * 128 + lk * 2) ^ sw));
            bf16x8 k1 = *(const bf16x8*)(kc + ((row * 128 + 64 + lk * 2) ^ sw));
            s[j] = __builtin_amdgcn_mfma_f32_16x16x32_bf16(k0, qf[0], s[j], 0, 0, 0);
            s[j] = __builtin_amdgcn_mfma_f32_16x16x32_bf16(k1, qf[1], s[j], 0, 0, 0);
        }

        float rm01 = fmaxf(fmaxf(s[0][0], s[0][1]), fmaxf(s[0][2], s[0][3]));
        float rm23 = fmaxf(fmaxf(s[1][0], s[1][1]), fmaxf(s[1][2], s[1][3]));
        float rm45 = fmaxf(fmaxf(s[2][0], s[2][1]), fmaxf(s[2][2], s[2][3]));
        float rm67 = fmaxf(fmaxf(s[3][0], s[3][1]), fmaxf(s[3][2], s[3][3]));
        float rm = fmaxf(fmaxf(rm01, rm23), fmaxf(rm45, rm67));
        rm = fmaxf(rm, __shfl_xor(rm, 16));
        rm = fmaxf(rm, __shfl_xor(rm, 32));

        if (__any(rm > m_s + 8.f)) {
            float mnew = fmaxf(m_s, rm);
            float fac_s = exp2f(m_s - mnew);
            m_s = mnew;
#pragma unroll
            for (int r = 0; r < 4; r++) {
                float fv = __shfl(fac_s, 4 * lg + r);
                l_v[r] *= fv;
#pragma unroll
                for (int j = 0; j < 4; j++) oacc[j][r] *= fv;
            }
        }

#pragma unroll
        for (int j = 0; j < 4; j++) {
            ushort4 pk;
            pk.x = f2b(exp2f(s[j][0] - m_s));
            pk.y = f2b(exp2f(s[j][1] - m_s));
            pk.z = f2b(exp2f(s[j][2] - m_s));
            pk.w = f2b(exp2f(s[j][3] - m_s));
            *(ushort4*)(pwb + pwr[j]) = pk;
        }

        f32x4 sacc = {};
#pragma unroll
        for (int ks = 0; ks < 2; ks++) {
            bf16x8 pa = *(const bf16x8*)(pwb + prd[ks]);
            sacc = __builtin_amdgcn_mfma_f32_16x16x32_bf16(pa, vone, sacc, 0, 0, 0);
#pragma unroll
            for (int j2 = 0; j2 < 4; j2++) {
                bf16x8 vb = *(const bf16x8*)(vc + vb_in[ks] + j2 * 2048);
                oacc[j2] = __builtin_amdgcn_mfma_f32_16x16x32_bf16(pa, vb, oacc[j2], 0, 0, 0);
            }
        }
#pragma unroll
        for (int r = 0; r < 4; r++) l_v[r] += sacc[r];
        __syncthreads();
    }

#pragma unroll
    for (int j2 = 0; j2 < 4; j2++)
#pragma unroll
        for (int r = 0; r < 4; r++) {
            float o = oacc[j2][r] / l_v[r];
            int qrow = q0 + 16 * wave + 4 * lg + r;
            ob[((size_t)b * 1024 + qrow) * 1024 + hh * 64 + 16 * j2 + lr] = __float2bfloat16(o);
        }
}

// ---------------- host ----------------
extern "C" void kernel_launch(void* const* d_in, const int* in_sizes, int n_in,
                              void* d_out, int out_size, void* d_ws, size_t ws_size,
                              hipStream_t stream) {
    const float* x = (const float*)d_in[0];
    const float* c = (const float*)d_in[1];
    const float* w_ada = (const float*)d_in[3];
    const float* b_ada = (const float*)d_in[4];
    const float* w_qkv = (const float*)d_in[5];
    const float* b_qkv = (const float*)d_in[6];
    const float* w_proj = (const float*)d_in[7];
    const float* b_proj = (const float*)d_in[8];
    const float* w_fc1 = (const float*)d_in[9];
    const float* b_fc1 = (const float*)d_in[10];
    const float* w_fc2 = (const float*)d_in[11];
    const float* b_fc2 = (const float*)d_in[12];
    float* out = (float*)d_out;

    char* p = (char*)d_ws;
    bf16* w_ada_t = (bf16*)p;  p += (size_t)6144 * 1024 * 2;
    bf16* w_qkv_t = (bf16*)p;  p += (size_t)3072 * 1024 * 2;
    bf16* w_proj_t = (bf16*)p; p += (size_t)1024 * 1024 * 2;
    bf16* w_fc1_t = (bf16*)p;  p += (size_t)4096 * 1024 * 2;
    bf16* w_fc2_t = (bf16*)p;  p += (size_t)1024 * 4096 * 2;
    bf16* mod = (bf16*)p;      p += (size_t)4096 * 6144 * 2;
    float* x1 = (float*)p;     p += (size_t)4096 * 1024 * 4;
    bf16* hbuf = (bf16*)p;     p += (size_t)4096 * 1024 * 2;
    bf16* qbuf = (bf16*)p;     p += (size_t)64 * 1024 * 64 * 2;
    bf16* kbuf = (bf16*)p;     p += (size_t)64 * 1024 * 64 * 2;
    bf16* vtbuf = (bf16*)p;    p += (size_t)64 * 64 * 1024 * 2;
    bf16* attnout = (bf16*)p;  p += (size_t)4096 * 1024 * 2;
    bf16* fc1out = qbuf;  // overlays qbuf..attnout (exactly 4096*4096*2 bytes)
    size_t base_need = (size_t)(p - (char*)d_ws);
    float* part = (float*)p;   // split-K partials: 2 x [4096,1024] f32 = 33.6 MB
    size_t ext_need = base_need + (size_t)2 * 4096 * 1024 * 4;

    if (ws_size < base_need) return;  // fail loudly (output stays poisoned)
    const bool big = ws_size >= ext_need;

    // prep: all weight transposes + silu in one launch (vectorized 64x64 tiles)
    k_prep<<<8704, 256, 0, stream>>>(w_ada, w_qkv, w_proj, w_fc1, w_fc2, c,
                                     w_ada_t, w_qkv_t, w_proj_t, w_fc1_t, w_fc2_t, hbuf);

    // mod = silu(c) @ w_ada + b_ada            [4096 x 6144]
    k_gemm128<EPI_BF16><<<1536, 128, 0, stream>>>(
        hbuf, w_ada_t, b_ada, 4096, 6144, 1024, 1024, mod,
        nullptr, nullptr, nullptr, nullptr, nullptr, 0, nullptr);

    // h = modulate(LN(x), shift_msa, scale_msa)
    k_ln_mod<<<4096, 256, 0, stream>>>(x, mod, hbuf, 0, 1024);

    // qkv [4096 x 3072]
    k_gemm128<EPI_QKV><<<768, 128, 0, stream>>>(
        hbuf, w_qkv_t, b_qkv, 4096, 3072, 1024, 1024, nullptr,
        qbuf, kbuf, vtbuf, nullptr, nullptr, 0, nullptr);

    k_attn<<<1024, 256, 0, stream>>>(qbuf, kbuf, vtbuf, attnout);

    // x1 = x + gate_msa * (attn @ w_proj + b_proj); h = modulate(LN(x1), mlp)
    if (big) {
        k_gemm128<EPI_PART><<<dim3(256, 2), 128, 0, stream>>>(
            attnout, w_proj_t, b_proj, 4096, 1024, 1024, 512, nullptr,
            nullptr, nullptr, nullptr, nullptr, nullptr, 0, part);
        k_reduce_ln<<<4096, 256, 0, stream>>>(part, x, mod, b_proj, x1, hbuf,
                                              2048, 3072, 4096);
    } else {
        k_gemm128<EPI_RES><<<256, 128, 0, stream>>>(
            attnout, w_proj_t, b_proj, 4096, 1024, 1024, 1024, nullptr,
            nullptr, nullptr, nullptr, x, mod, 2048, x1);
        k_ln_mod<<<4096, 256, 0, stream>>>(x1, mod, hbuf, 3072, 4096);
    }

    // fc1 + gelu [4096 x 4096]
    k_gemm128<EPI_GELU><<<1024, 128, 0, stream>>>(
        hbuf, w_fc1_t, b_fc1, 4096, 4096, 1024, 1024, fc1out,
        nullptr, nullptr, nullptr, nullptr, nullptr, 0, nullptr);

    // out = x1 + gate_mlp * (gelu @ w_fc2 + b_fc2)   [4096 x 1024]
    if (big) {
        k_gemm128<EPI_PART><<<dim3(256, 2), 128, 0, stream>>>(
            fc1out, w_fc2_t, b_fc2, 4096, 1024, 4096, 2048, nullptr,
            nullptr, nullptr, nullptr, nullptr, nullptr, 0, part);
        k_reduce4<2><<<2048, 256, 0, stream>>>(part, x1, mod, 5120, b_fc2, out);
    } else {
        k_gemm128<EPI_RES><<<256, 128, 0, stream>>>(
            fc1out, w_fc2_t, b_fc2, 4096, 1024, 4096, 4096, nullptr,
            nullptr, nullptr, nullptr, x1, mod, 5120, out);
    }
}

// Round 18
// 341.171 us; speedup vs baseline: 1.8539x; 1.8539x over previous
//
#include <hip/hip_runtime.h>
#include <hip/hip_bf16.h>

using bf16 = __hip_bfloat16;
typedef __attribute__((ext_vector_type(8))) short bf16x8;
typedef __attribute__((ext_vector_type(4))) float f32x4;

#define DEV static __device__ __forceinline__
#define CFENCE asm volatile("" ::: "memory")

DEV float b2f(unsigned short u) {
    unsigned int v = ((unsigned int)u) << 16;
    float f;
    __builtin_memcpy(&f, &v, 4);
    return f;
}
DEV unsigned short f2b(float f) {
    union { bf16 h; unsigned short u; } cv;
    cv.h = __float2bfloat16(f);
    return cv.u;
}

DEV void gload_lds16(const void* g, void* l) {
    __builtin_amdgcn_global_load_lds((__attribute__((address_space(1))) void*)g,
                                     (__attribute__((address_space(3))) void*)l, 16, 0, 0);
}

// ---------------- prep: 5 weight transposes + silu(c), one launch ----------------
DEV void wcast_tile64(float (*tile)[65], const float* __restrict__ w, bf16* __restrict__ wt,
                      int K, int N, int id, int tid) {
    const int gxN = N >> 6;
    const int n0 = (id % gxN) << 6, k0 = (id / gxN) << 6;
    const int r = tid >> 4, c4 = (tid & 15) << 2;
#pragma unroll
    for (int i = 0; i < 4; i++) {
        float4 v = *(const float4*)(w + (size_t)(k0 + r + 16 * i) * N + n0 + c4);
        tile[r + 16 * i][c4] = v.x;
        tile[r + 16 * i][c4 + 1] = v.y;
        tile[r + 16 * i][c4 + 2] = v.z;
        tile[r + 16 * i][c4 + 3] = v.w;
    }
    __syncthreads();
#pragma unroll
    for (int i = 0; i < 4; i++) {
        int rn = r + 16 * i;
        ushort4 o;
        o.x = f2b(tile[c4][rn]);
        o.y = f2b(tile[c4 + 1][rn]);
        o.z = f2b(tile[c4 + 2][rn]);
        o.w = f2b(tile[c4 + 3][rn]);
        *(ushort4*)(wt + (size_t)(n0 + rn) * K + k0 + c4) = o;
    }
}

__global__ __launch_bounds__(256) void k_prep(
    const float* __restrict__ w_ada, const float* __restrict__ w_qkv,
    const float* __restrict__ w_proj, const float* __restrict__ w_fc1,
    const float* __restrict__ w_fc2, const float* __restrict__ c,
    bf16* __restrict__ o_ada, bf16* __restrict__ o_qkv, bf16* __restrict__ o_proj,
    bf16* __restrict__ o_fc1, bf16* __restrict__ o_fc2, bf16* __restrict__ o_silu) {
    __shared__ float tile[64][65];
    const int bid = blockIdx.x;
    const int tid = threadIdx.x;
    if (bid < 1536) {
        wcast_tile64(tile, w_ada, o_ada, 1024, 6144, bid, tid);
    } else if (bid < 2304) {
        wcast_tile64(tile, w_qkv, o_qkv, 1024, 3072, bid - 1536, tid);
    } else if (bid < 2560) {
        wcast_tile64(tile, w_proj, o_proj, 1024, 1024, bid - 2304, tid);
    } else if (bid < 3584) {
        wcast_tile64(tile, w_fc1, o_fc1, 1024, 4096, bid - 2560, tid);
    } else if (bid < 4608) {
        wcast_tile64(tile, w_fc2, o_fc2, 4096, 1024, bid - 3584, tid);
    } else {
        int i = (bid - 4608) * 256 + tid;
        float4 v = ((const float4*)c)[i];
        float a[4] = {v.x, v.y, v.z, v.w};
        ushort4 r;
        unsigned short* rp = (unsigned short*)&r;
#pragma unroll
        for (int j = 0; j < 4; j++) {
            float s = a[j] / (1.f + __expf(-a[j]));
            rp[j] = f2b(s);
        }
        ((ushort4*)o_silu)[i] = r;
    }
}

// ---------------- LayerNorm + modulate -> bf16 ----------------
__global__ __launch_bounds__(256) void k_ln_mod(const float* __restrict__ x,
                                                const bf16* __restrict__ mod,
                                                bf16* __restrict__ h,
                                                int shift_off, int scale_off) {
    int row = blockIdx.x;
    int t = threadIdx.x;
    float4 v = ((const float4*)(x + (size_t)row * 1024))[t];
    float sum = v.x + v.y + v.z + v.w;
    float sq = v.x * v.x + v.y * v.y + v.z * v.z + v.w * v.w;
#pragma unroll
    for (int off = 32; off > 0; off >>= 1) {
        sum += __shfl_xor(sum, off);
        sq += __shfl_xor(sq, off);
    }
    __shared__ float s_sum[4], s_sq[4];
    if ((t & 63) == 0) { s_sum[t >> 6] = sum; s_sq[t >> 6] = sq; }
    __syncthreads();
    sum = s_sum[0] + s_sum[1] + s_sum[2] + s_sum[3];
    sq = s_sq[0] + s_sq[1] + s_sq[2] + s_sq[3];
    float mu = sum * (1.f / 1024.f);
    float var = sq * (1.f / 1024.f) - mu * mu;
    float rstd = rsqrtf(var + 1e-6f);
    const unsigned short* mrow = (const unsigned short*)mod + (size_t)row * 6144;
    ushort4 sh = ((const ushort4*)(mrow + shift_off))[t];
    ushort4 sc = ((const ushort4*)(mrow + scale_off))[t];
    unsigned short shs[4] = {sh.x, sh.y, sh.z, sh.w};
    unsigned short scs[4] = {sc.x, sc.y, sc.z, sc.w};
    float a[4] = {v.x, v.y, v.z, v.w};
    ushort4 r;
    unsigned short* rp = (unsigned short*)&r;
#pragma unroll
    for (int j = 0; j < 4; j++) {
        float nv = (a[j] - mu) * rstd;
        rp[j] = f2b(nv * (1.f + b2f(scs[j])) + b2f(shs[j]));
    }
    ((ushort4*)(h + (size_t)row * 1024))[t] = r;
}

enum { EPI_BF16 = 0, EPI_QKV = 1, EPI_RES = 2, EPI_GELU = 3, EPI_PART = 4 };

// bijective XCD-chunked + 8-wide column-group decomposition (works for any gx)
DEV void grid_decomp(int bid, int gx, int gy, int& by, int& bx) {
    const int nwg = gx * gy, cpx = nwg >> 3;  // requires nwg % 8 == 0
    const int wg = (bid & 7) * cpx + (bid >> 3);
    const int gspan = 8 * gy;
    const int grp = wg / gspan, rem = wg - grp * gspan;
    const int rest = gx - grp * 8;
    const int gw = rest < 8 ? rest : 8;  // last group may be narrower
    by = rem / gw;
    bx = grp * 8 + (rem - by * gw);
}

// ---------------- 128x128 GEMM, 2-wave blocks, wave-tile 128x64 ----------------
// LDS bytes/FLOP = 0.75x of the 64x64 scheme (measured binding pipe: LDS reads ~100%).
// (128,1): 512-VGPR budget so the ~196-reg live set allocates WITHOUT spill
// (R14: (256,4) clamp->64 VGPR->spill; R17: (128,2) clamp->128->spill).
// Runtime still packs 2 waves/SIMD (512/~200>=2) -> 4 blocks/CU.
template <int EPI>
__global__ __launch_bounds__(128, 1) void k_gemm128(
    const bf16* __restrict__ A, const bf16* __restrict__ Bt, const float* __restrict__ bias,
    int M, int N, int K, int kseg,
    bf16* __restrict__ outb,
    bf16* __restrict__ qo, bf16* __restrict__ ko, bf16* __restrict__ vto,
    const float* __restrict__ resid, const bf16* __restrict__ mod, int gate_off,
    float* __restrict__ outf) {
    __shared__ char lds[32768];  // A[128][64] 16K + B[128][64] 16K
    const int tid = threadIdx.x, wave = tid >> 6, lane = tid & 63;
    const int lr = lane & 15, lg = lane >> 4;

    int by, bx;
    grid_decomp((int)blockIdx.x, N >> 7, M >> 7, by, bx);
    const int row0 = by << 7, col0 = bx << 7;
    const int seg = blockIdx.y;

    f32x4 acc[8][4] = {};

    const size_t Kb = (size_t)K * 2;
    const size_t rowstep = Kb << 4;  // 16 rows
    const char* Ag = (const char*)A + (size_t)row0 * Kb + (size_t)seg * kseg * 2;
    const char* Bg = (const char*)Bt + (size_t)col0 * Kb + (size_t)seg * kseg * 2;

    // staging: 128 threads; thread covers rows grow+16i (i=0..7), 16B chunk (tid&7)
    const int grow = tid >> 3;
    const unsigned gsw = (unsigned)(((tid & 7) ^ (grow & 7)) << 4);
    const char* gA0 = Ag + (size_t)grow * Kb + gsw;
    const char* gB0 = Bg + (size_t)grow * Kb + gsw;

    auto stage = [&](int kt) {
        char* d = lds + (tid << 4);
        const size_t ko = (size_t)kt * 128;
#pragma unroll
        for (int i = 0; i < 8; i++)
            gload_lds16(gA0 + i * rowstep + ko, d + i * 2048);
#pragma unroll
        for (int i = 0; i < 8; i++)
            gload_lds16(gB0 + i * rowstep + ko, d + 16384 + i * 2048);
    };

    // LDS read bases (lane-constant swizzle: frag row = 16*m + lr -> row&7 == lr&7)
    const unsigned sw = (unsigned)((lr & 7) << 4);
    const unsigned swz0 = ((unsigned)(lg * 16)) ^ sw;        // kk=0
    const unsigned swz1 = ((unsigned)(64 + lg * 16)) ^ sw;   // kk=1
    const unsigned aoff = (unsigned)(lr * 128);
    const unsigned boff = (unsigned)(16384 + wave * 8192 + lr * 128);

    stage(0);
    const int NT = kseg >> 6;
    asm volatile("s_waitcnt vmcnt(0)" ::: "memory");
    __builtin_amdgcn_s_barrier();
    CFENCE;

    for (int kt = 0; kt < NT; ++kt) {
        bf16x8 a0[8], a1[8], b0[4], b1[4];
#pragma unroll
        for (int m = 0; m < 8; m++) {
            a0[m] = *(const bf16x8*)(lds + aoff + m * 2048 + swz0);
            a1[m] = *(const bf16x8*)(lds + aoff + m * 2048 + swz1);
        }
#pragma unroll
        for (int nj = 0; nj < 4; nj++) {
            b0[nj] = *(const bf16x8*)(lds + boff + nj * 2048 + swz0);
            b1[nj] = *(const bf16x8*)(lds + boff + nj * 2048 + swz1);
        }
        asm volatile("s_waitcnt lgkmcnt(0)" ::: "memory");
        __builtin_amdgcn_s_barrier();  // all waves finished reading the buffer
        CFENCE;
        if (kt + 1 < NT) stage(kt + 1);  // write same buffer, overlaps MFMA below
        __builtin_amdgcn_s_setprio(1);
#pragma unroll
        for (int m = 0; m < 8; m++)
#pragma unroll
            for (int nj = 0; nj < 4; nj++) {
                acc[m][nj] = __builtin_amdgcn_mfma_f32_16x16x32_bf16(a0[m], b0[nj], acc[m][nj], 0, 0, 0);
                acc[m][nj] = __builtin_amdgcn_mfma_f32_16x16x32_bf16(a1[m], b1[nj], acc[m][nj], 0, 0, 0);
            }
        __builtin_amdgcn_s_setprio(0);
        CFENCE;
        asm volatile("s_waitcnt vmcnt(0)" ::: "memory");
        __builtin_amdgcn_s_barrier();  // kt+1 tile fully landed
        CFENCE;
    }

    // epilogue: wave covers rows row0..+127, cols col0 + wave*64 .. +63
    const int rbase = row0 + 4 * lg;
    const int cbase = col0 + wave * 64 + lr;
#pragma unroll
    for (int mi = 0; mi < 8; mi++) {
#pragma unroll
        for (int nj = 0; nj < 4; nj++) {
            int col = cbase + 16 * nj;
            float bs = (EPI == EPI_PART) ? 0.f : bias[col];
#pragma unroll
            for (int r = 0; r < 4; r++) {
                int row = rbase + 16 * mi + r;
                float v = acc[mi][nj][r] + bs;
                if constexpr (EPI == EPI_BF16) {
                    outb[(size_t)row * N + col] = __float2bfloat16(v);
                } else if constexpr (EPI == EPI_GELU) {
                    float u = 0.7978845608f * (v + 0.044715f * v * v * v);
                    float e = __expf(2.f * u);
                    float th = 1.f - 2.f / (e + 1.f);
                    outb[(size_t)row * N + col] = __float2bfloat16(0.5f * v * (1.f + th));
                } else if constexpr (EPI == EPI_RES) {
                    float gate = b2f(((const unsigned short*)mod)[(size_t)row * 6144 + gate_off + col]);
                    outf[(size_t)row * N + col] = resid[(size_t)row * N + col] + gate * v;
                } else if constexpr (EPI == EPI_PART) {
                    outf[((size_t)seg * M + row) * N + col] = v;
                } else {  // EPI_QKV
                    int tt = col >> 10, hh = (col >> 6) & 15, d = col & 63;
                    int bb = row >> 10, ll = row & 1023;
                    size_t bh = (size_t)bb * 16 + hh;
                    bf16 bv = __float2bfloat16(v);
                    if (tt == 0) qo[(bh * 1024 + ll) * 64 + d] = bv;
                    else if (tt == 1) ko[(bh * 1024 + ll) * 64 + d] = bv;
                    else vto[(bh * 64 + d) * 1024 + ll] = bv;
                }
            }
        }
    }
}

// ---------------- split-K reduce: out = resid + gate * (sum partials + bias) ----------------
template <int NS>
__global__ __launch_bounds__(256) void k_reduce4(
    const float* __restrict__ part, const float* __restrict__ resid,
    const bf16* __restrict__ mod, int gate_off, const float* __restrict__ bias,
    float* __restrict__ out) {
    const int total4 = 4096 * 1024 / 4;
    for (int i = blockIdx.x * 256 + threadIdx.x; i < total4; i += gridDim.x * 256) {
        int row = i >> 8;
        int c4 = (i & 255) << 2;
        float4 s = ((const float4*)part)[i];
#pragma unroll
        for (int sg = 1; sg < NS; sg++) {
            float4 t = ((const float4*)part)[(size_t)sg * total4 + i];
            s.x += t.x; s.y += t.y; s.z += t.z; s.w += t.w;
        }
        float4 bi = *(const float4*)(bias + c4);
        ushort4 g = *(const ushort4*)((const unsigned short*)mod + (size_t)row * 6144 + gate_off + c4);
        float4 rs = ((const float4*)resid)[i];
        float4 o;
        o.x = rs.x + b2f(g.x) * (s.x + bi.x);
        o.y = rs.y + b2f(g.y) * (s.y + bi.y);
        o.z = rs.z + b2f(g.z) * (s.z + bi.z);
        o.w = rs.w + b2f(g.w) * (s.w + bi.w);
        ((float4*)out)[i] = o;
    }
}

// ---------------- fused: x1 = resid + gate*(sum part + bias); h = modulate(LN(x1)) ----
__global__ __launch_bounds__(256) void k_reduce_ln(
    const float* __restrict__ part, const float* __restrict__ resid,
    const bf16* __restrict__ mod, const float* __restrict__ bias,
    float* __restrict__ x1, bf16* __restrict__ h,
    int gate_off, int shift_off, int scale_off) {
    const int row = blockIdx.x, t = threadIdx.x;
    const int total4 = 4096 * 1024 / 4;
    const int i = row * 256 + t;
    const unsigned short* mrow = (const unsigned short*)mod + (size_t)row * 6144;

    float4 s = ((const float4*)part)[i];
    float4 s1 = ((const float4*)part)[total4 + i];
    s.x += s1.x; s.y += s1.y; s.z += s1.z; s.w += s1.w;
    float4 bi = ((const float4*)bias)[t];
    ushort4 g = ((const ushort4*)(mrow + gate_off))[t];
    float4 rs = ((const float4*)resid)[i];
    float4 xv;
    xv.x = rs.x + b2f(g.x) * (s.x + bi.x);
    xv.y = rs.y + b2f(g.y) * (s.y + bi.y);
    xv.z = rs.z + b2f(g.z) * (s.z + bi.z);
    xv.w = rs.w + b2f(g.w) * (s.w + bi.w);
    ((float4*)x1)[i] = xv;

    float sum = xv.x + xv.y + xv.z + xv.w;
    float sq = xv.x * xv.x + xv.y * xv.y + xv.z * xv.z + xv.w * xv.w;
#pragma unroll
    for (int off = 32; off > 0; off >>= 1) {
        sum += __shfl_xor(sum, off);
        sq += __shfl_xor(sq, off);
    }
    __shared__ float s_sum[4], s_sq[4];
    if ((t & 63) == 0) { s_sum[t >> 6] = sum; s_sq[t >> 6] = sq; }
    __syncthreads();
    sum = s_sum[0] + s_sum[1] + s_sum[2] + s_sum[3];
    sq = s_sq[0] + s_sq[1] + s_sq[2] + s_sq[3];
    float mu = sum * (1.f / 1024.f);
    float var = sq * (1.f / 1024.f) - mu * mu;
    float rstd = rsqrtf(var + 1e-6f);
    ushort4 sh = ((const ushort4*)(mrow + shift_off))[t];
    ushort4 sc = ((const ushort4*)(mrow + scale_off))[t];
    unsigned short shs[4] = {sh.x, sh.y, sh.z, sh.w};
    unsigned short scs[4] = {sc.x, sc.y, sc.z, sc.w};
    float a[4] = {xv.x, xv.y, xv.z, xv.w};
    ushort4 r;
    unsigned short* rp = (unsigned short*)&r;
#pragma unroll
    for (int j = 0; j < 4; j++) {
        float nv = (a[j] - mu) * rstd;
        rp[j] = f2b(nv * (1.f + b2f(scs[j])) + b2f(shs[j]));
    }
    ((ushort4*)(h + (size_t)row * 1024))[t] = r;
}

// ---------------- flash attention: swapped QK^T (lane-local softmax) ----------------
__global__ __launch_bounds__(256) void k_attn(const bf16* __restrict__ qb,
                                              const bf16* __restrict__ kb,
                                              const bf16* __restrict__ vtb,
                                              bf16* __restrict__ ob) {
    __shared__ bf16 Ks[2][4096];
    __shared__ bf16 Vs[2][4096];
    __shared__ bf16 Ps[4][1024];
    const int tid = threadIdx.x, wave = tid >> 6, lane = tid & 63;
    const int flat = blockIdx.x;
    const int wg = (flat & 7) * 128 + (flat >> 3);
    const int bh = wg >> 4;
    const int q0 = (wg & 15) * 64;
    const int b = bh >> 4, hh = bh & 15;
    const int lr = lane & 15, lg = lane >> 4, lk = lg * 8;

    const char* kbase = (const char*)(kb + (size_t)bh * 65536);
    const char* vbase = (const char*)(vtb + (size_t)bh * 65536);

    const int srow = tid >> 3;
    const int schunk = (tid & 7) ^ (srow & 7);

    bf16x8 qf[2];
    {
        const float C2 = 0.18033688f;  // 0.125 * log2(e)
        const bf16* qp = qb + ((size_t)bh * 1024 + q0 + 16 * wave + lr) * 64 + lk;
        bf16x8 t0 = *(const bf16x8*)qp;
        bf16x8 t1 = *(const bf16x8*)(qp + 32);
#pragma unroll
        for (int e = 0; e < 8; e++) {
            qf[0][e] = f2b(b2f((unsigned short)t0[e]) * C2);
            qf[1][e] = f2b(b2f((unsigned short)t1[e]) * C2);
        }
    }

    f32x4 oacc[4] = {};
    f32x4 l_v = {};
    float m_s = -1e30f;

    char* pwb = (char*)&Ps[wave][0];
    const unsigned psw = (unsigned)((lr & 7) << 4);
    unsigned pwr[4], prd[2];
#pragma unroll
    for (int j = 0; j < 4; j++) pwr[j] = ((unsigned)(lr * 128 + 32 * j + 8 * lg)) ^ psw;
#pragma unroll
    for (int ks = 0; ks < 2; ks++) prd[ks] = ((unsigned)(lr * 128 + 64 * ks + 16 * lg)) ^ psw;
    unsigned vb_in[2];
#pragma unroll
    for (int ks = 0; ks < 2; ks++)
        vb_in[ks] = ((unsigned)(128 * lr + 64 * ks + 2 * lk)) ^ psw;
    bf16x8 vone;
#pragma unroll
    for (int e = 0; e < 8; e++) vone[e] = (short)0x3F80;

    auto stage = [&](int kv0, int cur) {
#pragma unroll
        for (int i = 0; i < 2; i++) {
            int row = i * 32 + srow;
            gload_lds16(kbase + (size_t)(kv0 + row) * 128 + schunk * 16,
                        (char*)&Ks[cur][0] + wave * 1024 + i * 4096);
            gload_lds16(vbase + (size_t)row * 2048 + (size_t)kv0 * 2 + schunk * 16,
                        (char*)&Vs[cur][0] + wave * 1024 + i * 4096);
        }
    };

    stage(0, 0);
    __syncthreads();

    for (int t = 0; t < 16; ++t) {
        const int cur = t & 1;
        if (t + 1 < 16) stage((t + 1) * 64, cur ^ 1);
        const char* kc = (const char*)&Ks[cur][0];
        const char* vc = (const char*)&Vs[cur][0];

        f32x4 s[4] = {};
#pragma unroll
        for (int j = 0; j < 4; j++) {
            int row = 16 * j + lr;
            int sw = (row & 7) << 4;
            bf16x8 k0 = *(const bf16x8*)(kc + ((row * 128 + lk * 2) ^ sw));
            bf16x8 k1 = *(const bf16x8*)(kc + ((row * 128 + 64 + lk * 2) ^ sw));
            s[j] = __builtin_amdgcn_mfma_f32_16x16x32_bf16(k0, qf[0], s[j], 0, 0, 0);
            s[j] = __builtin_amdgcn_mfma_f32_16x16x32_bf16(k1, qf[1], s[j], 0, 0, 0);
        }

        float rm01 = fmaxf(fmaxf(s[0][0], s[0][1]), fmaxf(s[0][2], s[0][3]));
        float rm23 = fmaxf(fmaxf(s[1][0], s[1][1]), fmaxf(s[1][2], s[1][3]));
        float rm45 = fmaxf(fmaxf(s[2][0], s[2][1]), fmaxf(s[2][2], s[2][3]));
        float rm67 = fmaxf(fmaxf(s[3][0], s[3][1]), fmaxf(s[3][2], s[3][3]));
        float rm = fmaxf(fmaxf(rm01, rm23), fmaxf(rm45, rm67));
        rm = fmaxf(rm, __shfl_xor(rm, 16));
        rm = fmaxf(rm, __shfl_xor(rm, 32));

        if (__any(rm > m_s + 8.f)) {
            float mnew = fmaxf(m_s, rm);
            float fac_s = exp2f(m_s - mnew);
            m_s = mnew;
#pragma unroll
            for (int r = 0; r < 4; r++) {
                float fv = __shfl(fac_s, 4 * lg + r);
                l_v[r] *= fv;
#pragma unroll
                for (int j = 0; j < 4; j++) oacc[j][r] *= fv;
            }
        }

#pragma unroll
        for (int j = 0; j < 4; j++) {
            ushort4 pk;
            pk.x = f2b(exp2f(s[j][0] - m_s));
            pk.y = f2b(exp2f(s[j][1] - m_s));
            pk.z = f2b(exp2f(s[j][2] - m_s));
            pk.w = f2b(exp2f(s[j][3] - m_s));
            *(ushort4*)(pwb + pwr[j]) = pk;
        }

        f32x4 sacc = {};
#pragma unroll
        for (int ks = 0; ks < 2; ks++) {
            bf16x8 pa = *(const bf16x8*)(pwb + prd[ks]);
            sacc = __builtin_amdgcn_mfma_f32_16x16x32_bf16(pa, vone, sacc, 0, 0, 0);
#pragma unroll
            for (int j2 = 0; j2 < 4; j2++) {
                bf16x8 vb = *(const bf16x8*)(vc + vb_in[ks] + j2 * 2048);
                oacc[j2] = __builtin_amdgcn_mfma_f32_16x16x32_bf16(pa, vb, oacc[j2], 0, 0, 0);
            }
        }
#pragma unroll
        for (int r = 0; r < 4; r++) l_v[r] += sacc[r];
        __syncthreads();
    }

#pragma unroll
    for (int j2 = 0; j2 < 4; j2++)
#pragma unroll
        for (int r = 0; r < 4; r++) {
            float o = oacc[j2][r] / l_v[r];
            int qrow = q0 + 16 * wave + 4 * lg + r;
            ob[((size_t)b * 1024 + qrow) * 1024 + hh * 64 + 16 * j2 + lr] = __float2bfloat16(o);
        }
}

// ---------------- host ----------------
extern "C" void kernel_launch(void* const* d_in, const int* in_sizes, int n_in,
                              void* d_out, int out_size, void* d_ws, size_t ws_size,
                              hipStream_t stream) {
    const float* x = (const float*)d_in[0];
    const float* c = (const float*)d_in[1];
    const float* w_ada = (const float*)d_in[3];
    const float* b_ada = (const float*)d_in[4];
    const float* w_qkv = (const float*)d_in[5];
    const float* b_qkv = (const float*)d_in[6];
    const float* w_proj = (const float*)d_in[7];
    const float* b_proj = (const float*)d_in[8];
    const float* w_fc1 = (const float*)d_in[9];
    const float* b_fc1 = (const float*)d_in[10];
    const float* w_fc2 = (const float*)d_in[11];
    const float* b_fc2 = (const float*)d_in[12];
    float* out = (float*)d_out;

    char* p = (char*)d_ws;
    bf16* w_ada_t = (bf16*)p;  p += (size_t)6144 * 1024 * 2;
    bf16* w_qkv_t = (bf16*)p;  p += (size_t)3072 * 1024 * 2;
    bf16* w_proj_t = (bf16*)p; p += (size_t)1024 * 1024 * 2;
    bf16* w_fc1_t = (bf16*)p;  p += (size_t)4096 * 1024 * 2;
    bf16* w_fc2_t = (bf16*)p;  p += (size_t)1024 * 4096 * 2;
    bf16* mod = (bf16*)p;      p += (size_t)4096 * 6144 * 2;
    float* x1 = (float*)p;     p += (size_t)4096 * 1024 * 4;
    bf16* hbuf = (bf16*)p;     p += (size_t)4096 * 1024 * 2;
    bf16* qbuf = (bf16*)p;     p += (size_t)64 * 1024 * 64 * 2;
    bf16* kbuf = (bf16*)p;     p += (size_t)64 * 1024 * 64 * 2;
    bf16* vtbuf = (bf16*)p;    p += (size_t)64 * 64 * 1024 * 2;
    bf16* attnout = (bf16*)p;  p += (size_t)4096 * 1024 * 2;
    bf16* fc1out = qbuf;  // overlays qbuf..attnout (exactly 4096*4096*2 bytes)
    size_t base_need = (size_t)(p - (char*)d_ws);
    float* part = (float*)p;   // split-K partials: 2 x [4096,1024] f32 = 33.6 MB
    size_t ext_need = base_need + (size_t)2 * 4096 * 1024 * 4;

    if (ws_size < base_need) return;  // fail loudly (output stays poisoned)
    const bool big = ws_size >= ext_need;

    // prep: all weight transposes + silu in one launch (vectorized 64x64 tiles)
    k_prep<<<8704, 256, 0, stream>>>(w_ada, w_qkv, w_proj, w_fc1, w_fc2, c,
                                     w_ada_t, w_qkv_t, w_proj_t, w_fc1_t, w_fc2_t, hbuf);

    // mod = silu(c) @ w_ada + b_ada            [4096 x 6144]
    k_gemm128<EPI_BF16><<<1536, 128, 0, stream>>>(
        hbuf, w_ada_t, b_ada, 4096, 6144, 1024, 1024, mod,
        nullptr, nullptr, nullptr, nullptr, nullptr, 0, nullptr);

    // h = modulate(LN(x), shift_msa, scale_msa)
    k_ln_mod<<<4096, 256, 0, stream>>>(x, mod, hbuf, 0, 1024);

    // qkv [4096 x 3072]
    k_gemm128<EPI_QKV><<<768, 128, 0, stream>>>(
        hbuf, w_qkv_t, b_qkv, 4096, 3072, 1024, 1024, nullptr,
        qbuf, kbuf, vtbuf, nullptr, nullptr, 0, nullptr);

    k_attn<<<1024, 256, 0, stream>>>(qbuf, kbuf, vtbuf, attnout);

    // x1 = x + gate_msa * (attn @ w_proj + b_proj); h = modulate(LN(x1), mlp)
    if (big) {
        k_gemm128<EPI_PART><<<dim3(256, 2), 128, 0, stream>>>(
            attnout, w_proj_t, b_proj, 4096, 1024, 1024, 512, nullptr,
            nullptr, nullptr, nullptr, nullptr, nullptr, 0, part);
        k_reduce_ln<<<4096, 256, 0, stream>>>(part, x, mod, b_proj, x1, hbuf,
                                              2048, 3072, 4096);
    } else {
        k_gemm128<EPI_RES><<<256, 128, 0, stream>>>(
            attnout, w_proj_t, b_proj, 4096, 1024, 1024, 1024, nullptr,
            nullptr, nullptr, nullptr, x, mod, 2048, x1);
        k_ln_mod<<<4096, 256, 0, stream>>>(x1, mod, hbuf, 3072, 4096);
    }

    // fc1 + gelu [4096 x 4096]
    k_gemm128<EPI_GELU><<<1024, 128, 0, stream>>>(
        hbuf, w_fc1_t, b_fc1, 4096, 4096, 1024, 1024, fc1out,
        nullptr, nullptr, nullptr, nullptr, nullptr, 0, nullptr);

    // out = x1 + gate_mlp * (gelu @ w_fc2 + b_fc2)   [4096 x 1024]
    if (big) {
        k_gemm128<EPI_PART><<<dim3(256, 2), 128, 0, stream>>>(
            fc1out, w_fc2_t, b_fc2, 4096, 1024, 4096, 2048, nullptr,
            nullptr, nullptr, nullptr, nullptr, nullptr, 0, part);
        k_reduce4<2><<<2048, 256, 0, stream>>>(part, x1, mod, 5120, b_fc2, out);
    } else {
        k_gemm128<EPI_RES><<<256, 128, 0, stream>>>(
            fc1out, w_fc2_t, b_fc2, 4096, 1024, 4096, 4096, nullptr,
            nullptr, nullptr, nullptr, x1, mod, 5120, out);
    }
}

// Round 19
// 301.472 us; speedup vs baseline: 2.0981x; 1.1317x over previous
//
#include <hip/hip_runtime.h>
#include <hip/hip_bf16.h>

using bf16 = __hip_bfloat16;
typedef __attribute__((ext_vector_type(8))) short bf16x8;
typedef __attribute__((ext_vector_type(4))) float f32x4;

#define DEV static __device__ __forceinline__
#define CFENCE asm volatile("" ::: "memory")

DEV float b2f(unsigned short u) {
    unsigned int v = ((unsigned int)u) << 16;
    float f;
    __builtin_memcpy(&f, &v, 4);
    return f;
}
DEV unsigned short f2b(float f) {
    union { bf16 h; unsigned short u; } cv;
    cv.h = __float2bfloat16(f);
    return cv.u;
}

DEV void gload_lds16(const void* g, void* l) {
    __builtin_amdgcn_global_load_lds((__attribute__((address_space(1))) void*)g,
                                     (__attribute__((address_space(3))) void*)l, 16, 0, 0);
}

// ---------------- prep: 5 weight transposes + silu(c), one launch ----------------
DEV void wcast_tile64(float (*tile)[65], const float* __restrict__ w, bf16* __restrict__ wt,
                      int K, int N, int id, int tid) {
    const int gxN = N >> 6;
    const int n0 = (id % gxN) << 6, k0 = (id / gxN) << 6;
    const int r = tid >> 4, c4 = (tid & 15) << 2;
#pragma unroll
    for (int i = 0; i < 4; i++) {
        float4 v = *(const float4*)(w + (size_t)(k0 + r + 16 * i) * N + n0 + c4);
        tile[r + 16 * i][c4] = v.x;
        tile[r + 16 * i][c4 + 1] = v.y;
        tile[r + 16 * i][c4 + 2] = v.z;
        tile[r + 16 * i][c4 + 3] = v.w;
    }
    __syncthreads();
#pragma unroll
    for (int i = 0; i < 4; i++) {
        int rn = r + 16 * i;
        ushort4 o;
        o.x = f2b(tile[c4][rn]);
        o.y = f2b(tile[c4 + 1][rn]);
        o.z = f2b(tile[c4 + 2][rn]);
        o.w = f2b(tile[c4 + 3][rn]);
        *(ushort4*)(wt + (size_t)(n0 + rn) * K + k0 + c4) = o;
    }
}

__global__ __launch_bounds__(256) void k_prep(
    const float* __restrict__ w_ada, const float* __restrict__ w_qkv,
    const float* __restrict__ w_proj, const float* __restrict__ w_fc1,
    const float* __restrict__ w_fc2, const float* __restrict__ c,
    bf16* __restrict__ o_ada, bf16* __restrict__ o_qkv, bf16* __restrict__ o_proj,
    bf16* __restrict__ o_fc1, bf16* __restrict__ o_fc2, bf16* __restrict__ o_silu) {
    __shared__ float tile[64][65];
    const int bid = blockIdx.x;
    const int tid = threadIdx.x;
    if (bid < 1536) {
        wcast_tile64(tile, w_ada, o_ada, 1024, 6144, bid, tid);
    } else if (bid < 2304) {
        wcast_tile64(tile, w_qkv, o_qkv, 1024, 3072, bid - 1536, tid);
    } else if (bid < 2560) {
        wcast_tile64(tile, w_proj, o_proj, 1024, 1024, bid - 2304, tid);
    } else if (bid < 3584) {
        wcast_tile64(tile, w_fc1, o_fc1, 1024, 4096, bid - 2560, tid);
    } else if (bid < 4608) {
        wcast_tile64(tile, w_fc2, o_fc2, 4096, 1024, bid - 3584, tid);
    } else {
        int i = (bid - 4608) * 256 + tid;
        float4 v = ((const float4*)c)[i];
        float a[4] = {v.x, v.y, v.z, v.w};
        ushort4 r;
        unsigned short* rp = (unsigned short*)&r;
#pragma unroll
        for (int j = 0; j < 4; j++) {
            float s = a[j] / (1.f + __expf(-a[j]));
            rp[j] = f2b(s);
        }
        ((ushort4*)o_silu)[i] = r;
    }
}

// ---------------- LayerNorm + modulate -> bf16 ----------------
__global__ __launch_bounds__(256) void k_ln_mod(const float* __restrict__ x,
                                                const bf16* __restrict__ mod,
                                                bf16* __restrict__ h,
                                                int shift_off, int scale_off) {
    int row = blockIdx.x;
    int t = threadIdx.x;
    float4 v = ((const float4*)(x + (size_t)row * 1024))[t];
    float sum = v.x + v.y + v.z + v.w;
    float sq = v.x * v.x + v.y * v.y + v.z * v.z + v.w * v.w;
#pragma unroll
    for (int off = 32; off > 0; off >>= 1) {
        sum += __shfl_xor(sum, off);
        sq += __shfl_xor(sq, off);
    }
    __shared__ float s_sum[4], s_sq[4];
    if ((t & 63) == 0) { s_sum[t >> 6] = sum; s_sq[t >> 6] = sq; }
    __syncthreads();
    sum = s_sum[0] + s_sum[1] + s_sum[2] + s_sum[3];
    sq = s_sq[0] + s_sq[1] + s_sq[2] + s_sq[3];
    float mu = sum * (1.f / 1024.f);
    float var = sq * (1.f / 1024.f) - mu * mu;
    float rstd = rsqrtf(var + 1e-6f);
    const unsigned short* mrow = (const unsigned short*)mod + (size_t)row * 6144;
    ushort4 sh = ((const ushort4*)(mrow + shift_off))[t];
    ushort4 sc = ((const ushort4*)(mrow + scale_off))[t];
    unsigned short shs[4] = {sh.x, sh.y, sh.z, sh.w};
    unsigned short scs[4] = {sc.x, sc.y, sc.z, sc.w};
    float a[4] = {v.x, v.y, v.z, v.w};
    ushort4 r;
    unsigned short* rp = (unsigned short*)&r;
#pragma unroll
    for (int j = 0; j < 4; j++) {
        float nv = (a[j] - mu) * rstd;
        rp[j] = f2b(nv * (1.f + b2f(scs[j])) + b2f(shs[j]));
    }
    ((ushort4*)(h + (size_t)row * 1024))[t] = r;
}

enum { EPI_BF16 = 0, EPI_QKV = 1, EPI_RES = 2, EPI_GELU = 3, EPI_PART = 4 };

// bijective XCD-chunked + 8-wide column-group decomposition (works for any gx)
DEV void grid_decomp(int bid, int gx, int gy, int& by, int& bx) {
    const int nwg = gx * gy, cpx = nwg >> 3;  // requires nwg % 8 == 0
    const int wg = (bid & 7) * cpx + (bid >> 3);
    const int gspan = 8 * gy;
    const int grp = wg / gspan, rem = wg - grp * gspan;
    const int rest = gx - grp * 8;
    const int gw = rest < 8 ? rest : 8;  // last group may be narrower
    by = rem / gw;
    bx = grp * 8 + (rem - by * gw);
}

// ---------------- 128x128 GEMM, single-buffer LDS, 3 blocks/CU ----------------
// 256 threads = 4 waves (2M x 2N), wave-tile 64x64, BK=64, LDS 32 KiB (1 buffer).
// FINAL: (256,3), 84 VGPR, no spill. Wider wave-tiles (128x64) refuted 3x:
// R14 (256,4)->64 VGPR spill; R17 (128,2)->128 VGPR spill; R18 (128,1)->144
// VGPR + occupancy collapse to 9%. This is the session's practical floor.
template <int EPI>
__global__ __launch_bounds__(256, 3) void k_gemm128(
    const bf16* __restrict__ A, const bf16* __restrict__ Bt, const float* __restrict__ bias,
    int M, int N, int K, int kseg,
    bf16* __restrict__ outb,
    bf16* __restrict__ qo, bf16* __restrict__ ko, bf16* __restrict__ vto,
    const float* __restrict__ resid, const bf16* __restrict__ mod, int gate_off,
    float* __restrict__ outf) {
    __shared__ char lds[32768];  // A[128][64] 16K + B[128][64] 16K
    const int tid = threadIdx.x, wave = tid >> 6, lane = tid & 63;
    const int wr = wave >> 1, wc = wave & 1;
    const int lr = lane & 15, lg = lane >> 4;

    int by, bx;
    grid_decomp((int)blockIdx.x, N >> 7, M >> 7, by, bx);
    const int row0 = by << 7, col0 = bx << 7;
    const int seg = blockIdx.y;

    f32x4 acc[4][4] = {};

    const size_t Kb = (size_t)K * 2;
    const char* Ag = (const char*)A + (size_t)row0 * Kb + (size_t)seg * kseg * 2;
    const char* Bg = (const char*)Bt + (size_t)col0 * Kb + (size_t)seg * kseg * 2;

    const int grow = tid >> 3;
    const unsigned gsw = (unsigned)(((tid & 7) ^ (grow & 7)) << 4);
    const char* gA0 = Ag + (size_t)grow * Kb + gsw;
    const char* gA1 = Ag + (size_t)(grow + 32) * Kb + gsw;
    const char* gA2 = Ag + (size_t)(grow + 64) * Kb + gsw;
    const char* gA3 = Ag + (size_t)(grow + 96) * Kb + gsw;
    const char* gB0 = Bg + (size_t)grow * Kb + gsw;
    const char* gB1 = Bg + (size_t)(grow + 32) * Kb + gsw;
    const char* gB2 = Bg + (size_t)(grow + 64) * Kb + gsw;
    const char* gB3 = Bg + (size_t)(grow + 96) * Kb + gsw;

    auto stage = [&](int kt) {
        char* d = lds + (tid << 4);
        gload_lds16(gA0 + (size_t)kt * 128, d);
        gload_lds16(gA1 + (size_t)kt * 128, d + 4096);
        gload_lds16(gA2 + (size_t)kt * 128, d + 8192);
        gload_lds16(gA3 + (size_t)kt * 128, d + 12288);
        gload_lds16(gB0 + (size_t)kt * 128, d + 16384);
        gload_lds16(gB1 + (size_t)kt * 128, d + 20480);
        gload_lds16(gB2 + (size_t)kt * 128, d + 24576);
        gload_lds16(gB3 + (size_t)kt * 128, d + 28672);
    };

    const unsigned sw = (unsigned)((lr & 7) << 4);
    const unsigned swz0 = ((unsigned)(lg * 16)) ^ sw;
    const unsigned swz1 = ((unsigned)(64 + lg * 16)) ^ sw;
    const unsigned aoff = (unsigned)(wr * 8192 + lr * 128);
    const unsigned boff = (unsigned)(16384 + wc * 8192 + lr * 128);

    stage(0);
    const int NT = kseg >> 6;
    asm volatile("s_waitcnt vmcnt(0)" ::: "memory");
    __builtin_amdgcn_s_barrier();
    CFENCE;

    for (int kt = 0; kt < NT; ++kt) {
        bf16x8 a0[4], a1[4], b0[4], b1[4];
#pragma unroll
        for (int f = 0; f < 4; f++) {
            a0[f] = *(const bf16x8*)(lds + aoff + f * 2048 + swz0);
            a1[f] = *(const bf16x8*)(lds + aoff + f * 2048 + swz1);
        }
#pragma unroll
        for (int nj = 0; nj < 4; nj++) {
            b0[nj] = *(const bf16x8*)(lds + boff + nj * 2048 + swz0);
            b1[nj] = *(const bf16x8*)(lds + boff + nj * 2048 + swz1);
        }
        asm volatile("s_waitcnt lgkmcnt(0)" ::: "memory");
        __builtin_amdgcn_s_barrier();  // all waves finished reading the buffer
        CFENCE;
        if (kt + 1 < NT) stage(kt + 1);  // write same buffer, overlaps MFMA below
        __builtin_amdgcn_s_setprio(1);
#pragma unroll
        for (int f = 0; f < 4; f++)
#pragma unroll
            for (int nj = 0; nj < 4; nj++) {
                acc[f][nj] = __builtin_amdgcn_mfma_f32_16x16x32_bf16(a0[f], b0[nj], acc[f][nj], 0, 0, 0);
                acc[f][nj] = __builtin_amdgcn_mfma_f32_16x16x32_bf16(a1[f], b1[nj], acc[f][nj], 0, 0, 0);
            }
        __builtin_amdgcn_s_setprio(0);
        CFENCE;
        asm volatile("s_waitcnt vmcnt(0)" ::: "memory");
        __builtin_amdgcn_s_barrier();  // kt+1 tile fully landed
        CFENCE;
    }

    // epilogue
    const int rbase = row0 + wr * 64 + 4 * lg;
    const int cbase = col0 + wc * 64 + lr;
#pragma unroll
    for (int mi = 0; mi < 4; mi++) {
#pragma unroll
        for (int nj = 0; nj < 4; nj++) {
            int col = cbase + 16 * nj;
            float bs = (EPI == EPI_PART) ? 0.f : bias[col];
#pragma unroll
            for (int r = 0; r < 4; r++) {
                int row = rbase + 16 * mi + r;
                float v = acc[mi][nj][r] + bs;
                if constexpr (EPI == EPI_BF16) {
                    outb[(size_t)row * N + col] = __float2bfloat16(v);
                } else if constexpr (EPI == EPI_GELU) {
                    float u = 0.7978845608f * (v + 0.044715f * v * v * v);
                    float e = __expf(2.f * u);
                    float th = 1.f - 2.f / (e + 1.f);
                    outb[(size_t)row * N + col] = __float2bfloat16(0.5f * v * (1.f + th));
                } else if constexpr (EPI == EPI_RES) {
                    float gate = b2f(((const unsigned short*)mod)[(size_t)row * 6144 + gate_off + col]);
                    outf[(size_t)row * N + col] = resid[(size_t)row * N + col] + gate * v;
                } else if constexpr (EPI == EPI_PART) {
                    outf[((size_t)seg * M + row) * N + col] = v;
                } else {  // EPI_QKV
                    int tt = col >> 10, hh = (col >> 6) & 15, d = col & 63;
                    int bb = row >> 10, ll = row & 1023;
                    size_t bh = (size_t)bb * 16 + hh;
                    bf16 bv = __float2bfloat16(v);
                    if (tt == 0) qo[(bh * 1024 + ll) * 64 + d] = bv;
                    else if (tt == 1) ko[(bh * 1024 + ll) * 64 + d] = bv;
                    else vto[(bh * 64 + d) * 1024 + ll] = bv;
                }
            }
        }
    }
}

// ---------------- split-K reduce: out = resid + gate * (sum partials + bias) ----------------
template <int NS>
__global__ __launch_bounds__(256) void k_reduce4(
    const float* __restrict__ part, const float* __restrict__ resid,
    const bf16* __restrict__ mod, int gate_off, const float* __restrict__ bias,
    float* __restrict__ out) {
    const int total4 = 4096 * 1024 / 4;
    for (int i = blockIdx.x * 256 + threadIdx.x; i < total4; i += gridDim.x * 256) {
        int row = i >> 8;
        int c4 = (i & 255) << 2;
        float4 s = ((const float4*)part)[i];
#pragma unroll
        for (int sg = 1; sg < NS; sg++) {
            float4 t = ((const float4*)part)[(size_t)sg * total4 + i];
            s.x += t.x; s.y += t.y; s.z += t.z; s.w += t.w;
        }
        float4 bi = *(const float4*)(bias + c4);
        ushort4 g = *(const ushort4*)((const unsigned short*)mod + (size_t)row * 6144 + gate_off + c4);
        float4 rs = ((const float4*)resid)[i];
        float4 o;
        o.x = rs.x + b2f(g.x) * (s.x + bi.x);
        o.y = rs.y + b2f(g.y) * (s.y + bi.y);
        o.z = rs.z + b2f(g.z) * (s.z + bi.z);
        o.w = rs.w + b2f(g.w) * (s.w + bi.w);
        ((float4*)out)[i] = o;
    }
}

// ---------------- fused: x1 = resid + gate*(sum part + bias); h = modulate(LN(x1)) ----
__global__ __launch_bounds__(256) void k_reduce_ln(
    const float* __restrict__ part, const float* __restrict__ resid,
    const bf16* __restrict__ mod, const float* __restrict__ bias,
    float* __restrict__ x1, bf16* __restrict__ h,
    int gate_off, int shift_off, int scale_off) {
    const int row = blockIdx.x, t = threadIdx.x;
    const int total4 = 4096 * 1024 / 4;
    const int i = row * 256 + t;
    const unsigned short* mrow = (const unsigned short*)mod + (size_t)row * 6144;

    float4 s = ((const float4*)part)[i];
    float4 s1 = ((const float4*)part)[total4 + i];
    s.x += s1.x; s.y += s1.y; s.z += s1.z; s.w += s1.w;
    float4 bi = ((const float4*)bias)[t];
    ushort4 g = ((const ushort4*)(mrow + gate_off))[t];
    float4 rs = ((const float4*)resid)[i];
    float4 xv;
    xv.x = rs.x + b2f(g.x) * (s.x + bi.x);
    xv.y = rs.y + b2f(g.y) * (s.y + bi.y);
    xv.z = rs.z + b2f(g.z) * (s.z + bi.z);
    xv.w = rs.w + b2f(g.w) * (s.w + bi.w);
    ((float4*)x1)[i] = xv;

    float sum = xv.x + xv.y + xv.z + xv.w;
    float sq = xv.x * xv.x + xv.y * xv.y + xv.z * xv.z + xv.w * xv.w;
#pragma unroll
    for (int off = 32; off > 0; off >>= 1) {
        sum += __shfl_xor(sum, off);
        sq += __shfl_xor(sq, off);
    }
    __shared__ float s_sum[4], s_sq[4];
    if ((t & 63) == 0) { s_sum[t >> 6] = sum; s_sq[t >> 6] = sq; }
    __syncthreads();
    sum = s_sum[0] + s_sum[1] + s_sum[2] + s_sum[3];
    sq = s_sq[0] + s_sq[1] + s_sq[2] + s_sq[3];
    float mu = sum * (1.f / 1024.f);
    float var = sq * (1.f / 1024.f) - mu * mu;
    float rstd = rsqrtf(var + 1e-6f);
    ushort4 sh = ((const ushort4*)(mrow + shift_off))[t];
    ushort4 sc = ((const ushort4*)(mrow + scale_off))[t];
    unsigned short shs[4] = {sh.x, sh.y, sh.z, sh.w};
    unsigned short scs[4] = {sc.x, sc.y, sc.z, sc.w};
    float a[4] = {xv.x, xv.y, xv.z, xv.w};
    ushort4 r;
    unsigned short* rp = (unsigned short*)&r;
#pragma unroll
    for (int j = 0; j < 4; j++) {
        float nv = (a[j] - mu) * rstd;
        rp[j] = f2b(nv * (1.f + b2f(scs[j])) + b2f(shs[j]));
    }
    ((ushort4*)(h + (size_t)row * 1024))[t] = r;
}

// ---------------- flash attention: swapped QK^T (lane-local softmax) ----------------
__global__ __launch_bounds__(256) void k_attn(const bf16* __restrict__ qb,
                                              const bf16* __restrict__ kb,
                                              const bf16* __restrict__ vtb,
                                              bf16* __restrict__ ob) {
    __shared__ bf16 Ks[2][4096];
    __shared__ bf16 Vs[2][4096];
    __shared__ bf16 Ps[4][1024];
    const int tid = threadIdx.x, wave = tid >> 6, lane = tid & 63;
    const int flat = blockIdx.x;
    const int wg = (flat & 7) * 128 + (flat >> 3);
    const int bh = wg >> 4;
    const int q0 = (wg & 15) * 64;
    const int b = bh >> 4, hh = bh & 15;
    const int lr = lane & 15, lg = lane >> 4, lk = lg * 8;

    const char* kbase = (const char*)(kb + (size_t)bh * 65536);
    const char* vbase = (const char*)(vtb + (size_t)bh * 65536);

    const int srow = tid >> 3;
    const int schunk = (tid & 7) ^ (srow & 7);

    bf16x8 qf[2];
    {
        const float C2 = 0.18033688f;  // 0.125 * log2(e)
        const bf16* qp = qb + ((size_t)bh * 1024 + q0 + 16 * wave + lr) * 64 + lk;
        bf16x8 t0 = *(const bf16x8*)qp;
        bf16x8 t1 = *(const bf16x8*)(qp + 32);
#pragma unroll
        for (int e = 0; e < 8; e++) {
            qf[0][e] = f2b(b2f((unsigned short)t0[e]) * C2);
            qf[1][e] = f2b(b2f((unsigned short)t1[e]) * C2);
        }
    }

    f32x4 oacc[4] = {};
    f32x4 l_v = {};
    float m_s = -1e30f;

    char* pwb = (char*)&Ps[wave][0];
    const unsigned psw = (unsigned)((lr & 7) << 4);
    unsigned pwr[4], prd[2];
#pragma unroll
    for (int j = 0; j < 4; j++) pwr[j] = ((unsigned)(lr * 128 + 32 * j + 8 * lg)) ^ psw;
#pragma unroll
    for (int ks = 0; ks < 2; ks++) prd[ks] = ((unsigned)(lr * 128 + 64 * ks + 16 * lg)) ^ psw;
    unsigned vb_in[2];
#pragma unroll
    for (int ks = 0; ks < 2; ks++)
        vb_in[ks] = ((unsigned)(128 * lr + 64 * ks + 2 * lk)) ^ psw;
    bf16x8 vone;
#pragma unroll
    for (int e = 0; e < 8; e++) vone[e] = (short)0x3F80;

    auto stage = [&](int kv0, int cur) {
#pragma unroll
        for (int i = 0; i < 2; i++) {
            int row = i * 32 + srow;
            gload_lds16(kbase + (size_t)(kv0 + row) * 128 + schunk * 16,
                        (char*)&Ks[cur][0] + wave * 1024 + i * 4096);
            gload_lds16(vbase + (size_t)row * 2048 + (size_t)kv0 * 2 + schunk * 16,
                        (char*)&Vs[cur][0] + wave * 1024 + i * 4096);
        }
    };

    stage(0, 0);
    __syncthreads();

    for (int t = 0; t < 16; ++t) {
        const int cur = t & 1;
        if (t + 1 < 16) stage((t + 1) * 64, cur ^ 1);
        const char* kc = (const char*)&Ks[cur][0];
        const char* vc = (const char*)&Vs[cur][0];

        f32x4 s[4] = {};
#pragma unroll
        for (int j = 0; j < 4; j++) {
            int row = 16 * j + lr;
            int sw = (row & 7) << 4;
            bf16x8 k0 = *(const bf16x8*)(kc + ((row * 128 + lk * 2) ^ sw));
            bf16x8 k1 = *(const bf16x8*)(kc + ((row * 128 + 64 + lk * 2) ^ sw));
            s[j] = __builtin_amdgcn_mfma_f32_16x16x32_bf16(k0, qf[0], s[j], 0, 0, 0);
            s[j] = __builtin_amdgcn_mfma_f32_16x16x32_bf16(k1, qf[1], s[j], 0, 0, 0);
        }

        float rm01 = fmaxf(fmaxf(s[0][0], s[0][1]), fmaxf(s[0][2], s[0][3]));
        float rm23 = fmaxf(fmaxf(s[1][0], s[1][1]), fmaxf(s[1][2], s[1][3]));
        float rm45 = fmaxf(fmaxf(s[2][0], s[2][1]), fmaxf(s[2][2], s[2][3]));
        float rm67 = fmaxf(fmaxf(s[3][0], s[3][1]), fmaxf(s[3][2], s[3][3]));
        float rm = fmaxf(fmaxf(rm01, rm23), fmaxf(rm45, rm67));
        rm = fmaxf(rm, __shfl_xor(rm, 16));
        rm = fmaxf(rm, __shfl_xor(rm, 32));

        if (__any(rm > m_s + 8.f)) {
            float mnew = fmaxf(m_s, rm);
            float fac_s = exp2f(m_s - mnew);
            m_s = mnew;
#pragma unroll
            for (int r = 0; r < 4; r++) {
                float fv = __shfl(fac_s, 4 * lg + r);
                l_v[r] *= fv;
#pragma unroll
                for (int j = 0; j < 4; j++) oacc[j][r] *= fv;
            }
        }

#pragma unroll
        for (int j = 0; j < 4; j++) {
            ushort4 pk;
            pk.x = f2b(exp2f(s[j][0] - m_s));
            pk.y = f2b(exp2f(s[j][1] - m_s));
            pk.z = f2b(exp2f(s[j][2] - m_s));
            pk.w = f2b(exp2f(s[j][3] - m_s));
            *(ushort4*)(pwb + pwr[j]) = pk;
        }

        f32x4 sacc = {};
#pragma unroll
        for (int ks = 0; ks < 2; ks++) {
            bf16x8 pa = *(const bf16x8*)(pwb + prd[ks]);
            sacc = __builtin_amdgcn_mfma_f32_16x16x32_bf16(pa, vone, sacc, 0, 0, 0);
#pragma unroll
            for (int j2 = 0; j2 < 4; j2++) {
                bf16x8 vb = *(const bf16x8*)(vc + vb_in[ks] + j2 * 2048);
                oacc[j2] = __builtin_amdgcn_mfma_f32_16x16x32_bf16(pa, vb, oacc[j2], 0, 0, 0);
            }
        }
#pragma unroll
        for (int r = 0; r < 4; r++) l_v[r] += sacc[r];
        __syncthreads();
    }

#pragma unroll
    for (int j2 = 0; j2 < 4; j2++)
#pragma unroll
        for (int r = 0; r < 4; r++) {
            float o = oacc[j2][r] / l_v[r];
            int qrow = q0 + 16 * wave + 4 * lg + r;
            ob[((size_t)b * 1024 + qrow) * 1024 + hh * 64 + 16 * j2 + lr] = __float2bfloat16(o);
        }
}

// ---------------- host ----------------
extern "C" void kernel_launch(void* const* d_in, const int* in_sizes, int n_in,
                              void* d_out, int out_size, void* d_ws, size_t ws_size,
                              hipStream_t stream) {
    const float* x = (const float*)d_in[0];
    const float* c = (const float*)d_in[1];
    const float* w_ada = (const float*)d_in[3];
    const float* b_ada = (const float*)d_in[4];
    const float* w_qkv = (const float*)d_in[5];
    const float* b_qkv = (const float*)d_in[6];
    const float* w_proj = (const float*)d_in[7];
    const float* b_proj = (const float*)d_in[8];
    const float* w_fc1 = (const float*)d_in[9];
    const float* b_fc1 = (const float*)d_in[10];
    const float* w_fc2 = (const float*)d_in[11];
    const float* b_fc2 = (const float*)d_in[12];
    float* out = (float*)d_out;

    char* p = (char*)d_ws;
    bf16* w_ada_t = (bf16*)p;  p += (size_t)6144 * 1024 * 2;
    bf16* w_qkv_t = (bf16*)p;  p += (size_t)3072 * 1024 * 2;
    bf16* w_proj_t = (bf16*)p; p += (size_t)1024 * 1024 * 2;
    bf16* w_fc1_t = (bf16*)p;  p += (size_t)4096 * 1024 * 2;
    bf16* w_fc2_t = (bf16*)p;  p += (size_t)1024 * 4096 * 2;
    bf16* mod = (bf16*)p;      p += (size_t)4096 * 6144 * 2;
    float* x1 = (float*)p;     p += (size_t)4096 * 1024 * 4;
    bf16* hbuf = (bf16*)p;     p += (size_t)4096 * 1024 * 2;
    bf16* qbuf = (bf16*)p;     p += (size_t)64 * 1024 * 64 * 2;
    bf16* kbuf = (bf16*)p;     p += (size_t)64 * 1024 * 64 * 2;
    bf16* vtbuf = (bf16*)p;    p += (size_t)64 * 64 * 1024 * 2;
    bf16* attnout = (bf16*)p;  p += (size_t)4096 * 1024 * 2;
    bf16* fc1out = qbuf;  // overlays qbuf..attnout (exactly 4096*4096*2 bytes)
    size_t base_need = (size_t)(p - (char*)d_ws);
    float* part = (float*)p;   // split-K partials: 2 x [4096,1024] f32 = 33.6 MB
    size_t ext_need = base_need + (size_t)2 * 4096 * 1024 * 4;

    if (ws_size < base_need) return;  // fail loudly (output stays poisoned)
    const bool big = ws_size >= ext_need;

    // prep: all weight transposes + silu in one launch (vectorized 64x64 tiles)
    k_prep<<<8704, 256, 0, stream>>>(w_ada, w_qkv, w_proj, w_fc1, w_fc2, c,
                                     w_ada_t, w_qkv_t, w_proj_t, w_fc1_t, w_fc2_t, hbuf);

    // mod = silu(c) @ w_ada + b_ada            [4096 x 6144]
    k_gemm128<EPI_BF16><<<1536, 256, 0, stream>>>(
        hbuf, w_ada_t, b_ada, 4096, 6144, 1024, 1024, mod,
        nullptr, nullptr, nullptr, nullptr, nullptr, 0, nullptr);

    // h = modulate(LN(x), shift_msa, scale_msa)
    k_ln_mod<<<4096, 256, 0, stream>>>(x, mod, hbuf, 0, 1024);

    // qkv [4096 x 3072]
    k_gemm128<EPI_QKV><<<768, 256, 0, stream>>>(
        hbuf, w_qkv_t, b_qkv, 4096, 3072, 1024, 1024, nullptr,
        qbuf, kbuf, vtbuf, nullptr, nullptr, 0, nullptr);

    k_attn<<<1024, 256, 0, stream>>>(qbuf, kbuf, vtbuf, attnout);

    // x1 = x + gate_msa * (attn @ w_proj + b_proj); h = modulate(LN(x1), mlp)
    if (big) {
        k_gemm128<EPI_PART><<<dim3(256, 2), 256, 0, stream>>>(
            attnout, w_proj_t, b_proj, 4096, 1024, 1024, 512, nullptr,
            nullptr, nullptr, nullptr, nullptr, nullptr, 0, part);
        k_reduce_ln<<<4096, 256, 0, stream>>>(part, x, mod, b_proj, x1, hbuf,
                                              2048, 3072, 4096);
    } else {
        k_gemm128<EPI_RES><<<256, 256, 0, stream>>>(
            attnout, w_proj_t, b_proj, 4096, 1024, 1024, 1024, nullptr,
            nullptr, nullptr, nullptr, x, mod, 2048, x1);
        k_ln_mod<<<4096, 256, 0, stream>>>(x1, mod, hbuf, 3072, 4096);
    }

    // fc1 + gelu [4096 x 4096]
    k_gemm128<EPI_GELU><<<1024, 256, 0, stream>>>(
        hbuf, w_fc1_t, b_fc1, 4096, 4096, 1024, 1024, fc1out,
        nullptr, nullptr, nullptr, nullptr, nullptr, 0, nullptr);

    // out = x1 + gate_mlp * (gelu @ w_fc2 + b_fc2)   [4096 x 1024]
    if (big) {
        k_gemm128<EPI_PART><<<dim3(256, 2), 256, 0, stream>>>(
            fc1out, w_fc2_t, b_fc2, 4096, 1024, 4096, 2048, nullptr,
            nullptr, nullptr, nullptr, nullptr, nullptr, 0, part);
        k_reduce4<2><<<2048, 256, 0, stream>>>(part, x1, mod, 5120, b_fc2, out);
    } else {
        k_gemm128<EPI_RES><<<256, 256, 0, stream>>>(
            fc1out, w_fc2_t, b_fc2, 4096, 1024, 4096, 4096, nullptr,
            nullptr, nullptr, nullptr, x1, mod, 5120, out);
    }
}